// Round 11
// baseline (24.827 us; speedup 1.0000x reference)
//
#include <hip/hip_runtime.h>

// QuantizationLoss: sum over all elements of min(1, min_i |x - (i/127.5 - 1)|),
// i in [0,255]. Scan init = ones_like caps the distance at 1.0.
// Closed form: nearest level of the uniform grid on [-1,1], step 1/127.5:
//   r = clamp(rint((x+1)*127.5), 0, 255);  dist = min(1, |x - (r/127.5 - 1)|)
//
// Round 10 -> 11: VALU trim. Work in grid units y = (x+1)*127.5:
//   d' = min(|y - clamp(rint(y),0,255)|, 127.5);  sum d';  scale by 1/127.5
// once per thread at the end. 6 VALU ops/element instead of 7 (drops the
// second fma). k1 is at ~6.1 TB/s; fills show the fabric does 7.2 TB/s, so
// testing whether VALU issue pressure is shaving read BW.

#define BLOCK  512
#define UNROLL 16

typedef float vfloat4 __attribute__((ext_vector_type(4)));

__device__ __forceinline__ float qdist_gu(float x) {
    // distance in grid units (1 unit = 1/127.5), capped at 127.5 (=1.0 real)
    float y = __builtin_fmaf(x, 127.5f, 127.5f);   // (x+1)*127.5
    float r = rintf(y);                             // v_rndne
    r = fminf(fmaxf(r, 0.0f), 255.0f);              // v_med3
    return fminf(fabsf(y - r), 127.5f);             // v_sub + v_min(abs, )
}

__device__ __forceinline__ float qdist4(vfloat4 v) {
    return (qdist_gu(v.x) + qdist_gu(v.y)) + (qdist_gu(v.z) + qdist_gu(v.w));
}

__global__ __launch_bounds__(BLOCK) void ql_partial_kernel(
    const vfloat4* __restrict__ in4, int n4,
    const float* __restrict__ in_tail, int ntail,
    float* __restrict__ partial)
{
    // Block b owns [b*BLOCK*UNROLL, (b+1)*BLOCK*UNROLL) float4s; thread t
    // loads t + u*BLOCK (u = 0..15), all issued together (non-temporal).
    const int base = blockIdx.x * (BLOCK * UNROLL) + threadIdx.x;

    float a[UNROLL];
    #pragma unroll
    for (int u = 0; u < UNROLL; ++u) a[u] = 0.0f;

    if (base + (UNROLL - 1) * BLOCK < n4) {          // fast path: all in bounds
        vfloat4 v[UNROLL];
        #pragma unroll
        for (int u = 0; u < UNROLL; ++u)
            v[u] = __builtin_nontemporal_load(&in4[base + u * BLOCK]);
        #pragma unroll
        for (int u = 0; u < UNROLL; ++u) a[u] += qdist4(v[u]);
    } else {                                          // edge block
        #pragma unroll
        for (int u = 0; u < UNROLL; ++u) {
            int i = base + u * BLOCK;
            if (i < n4) a[u] += qdist4(__builtin_nontemporal_load(&in4[i]));
        }
    }

    // scalar tail (n not divisible by 4), first ntail threads of block 0
    if (blockIdx.x == 0 && threadIdx.x < ntail)
        a[0] += qdist_gu(in_tail[threadIdx.x]);

    float acc = 0.0f;
    #pragma unroll
    for (int u = 0; u < UNROLL; ++u) acc += a[u];
    acc *= (1.0f / 127.5f);                           // grid units -> real

    #pragma unroll
    for (int off = 32; off > 0; off >>= 1)
        acc += __shfl_down(acc, off, 64);

    __shared__ float smem[BLOCK / 64];
    int lane = threadIdx.x & 63;
    int wid  = threadIdx.x >> 6;
    if (lane == 0) smem[wid] = acc;
    __syncthreads();

    if (threadIdx.x == 0) {
        float s = 0.0f;
        #pragma unroll
        for (int w = 0; w < BLOCK / 64; ++w) s += smem[w];
        partial[blockIdx.x] = s;   // plain store, no atomics
    }
}

#define FBLOCK 1024
__global__ __launch_bounds__(FBLOCK) void ql_final_kernel(
    const float* __restrict__ partial, int np, float* __restrict__ out)
{
    float acc = 0.0f;
    const float2* p2 = (const float2*)partial;
    int np2 = np >> 1;
    for (int i = threadIdx.x; i < np2; i += FBLOCK) {
        float2 v = p2[i];
        acc += v.x + v.y;
    }
    if ((np & 1) && threadIdx.x == 0) acc += partial[np - 1];

    #pragma unroll
    for (int off = 32; off > 0; off >>= 1)
        acc += __shfl_down(acc, off, 64);

    __shared__ float smem[FBLOCK / 64];
    int lane = threadIdx.x & 63;
    int wid  = threadIdx.x >> 6;
    if (lane == 0) smem[wid] = acc;
    __syncthreads();

    if (threadIdx.x == 0) {
        float s = 0.0f;
        #pragma unroll
        for (int w = 0; w < FBLOCK / 64; ++w) s += smem[w];
        out[0] = s;                // overwrites poison; no memset needed
    }
}

extern "C" void kernel_launch(void* const* d_in, const int* in_sizes, int n_in,
                              void* d_out, int out_size, void* d_ws, size_t ws_size,
                              hipStream_t stream) {
    const float* x = (const float*)d_in[0];
    float* out     = (float*)d_out;
    float* partial = (float*)d_ws;
    int n = in_sizes[0];

    int n4    = n >> 2;
    int ntail = n & 3;
    const float* tail = x + (n4 << 2);

    int grid = (n4 + BLOCK * UNROLL - 1) / (BLOCK * UNROLL);   // 1024 for n4=8M
    int maxp = (int)(ws_size / sizeof(float));
    if (grid > maxp) grid = maxp;        // safety: partials must fit d_ws
    if (grid < 1) grid = 1;

    ql_partial_kernel<<<grid, BLOCK, 0, stream>>>(
        (const vfloat4*)x, n4, tail, ntail, partial);
    ql_final_kernel<<<1, FBLOCK, 0, stream>>>(partial, grid, out);
}